// Round 4
// baseline (2996.932 us; speedup 1.0000x reference)
//
#include <hip/hip_runtime.h>
#include <hip/hip_bf16.h>
#include <cstdint>

#define NB 16384   // batch
#define NM 256     // M
#define NN 1024    // N
#define NITER 16
#define TOPK 50

typedef __attribute__((ext_vector_type(8))) short short8;   // 8 bf16 = 4 VGPRs
typedef __attribute__((ext_vector_type(4))) float f32x4;

__device__ inline unsigned short f2bf(float x) {            // RNE fp32 -> bf16
    unsigned u = __float_as_uint(x);
    return (unsigned short)((u + 0x7FFFu + ((u >> 16) & 1u)) >> 16);
}
__device__ inline float bf2f(unsigned short h) {
    return __uint_as_float(((unsigned)h) << 16);
}
__device__ inline void gload16(const void* g, void* lds) {  // 16B global -> LDS
    __builtin_amdgcn_global_load_lds(
        (const __attribute__((address_space(1))) unsigned*)g,
        (__attribute__((address_space(3))) unsigned*)lds, 16, 0, 0);
}

// ------------- precompute: element-wise split of phi (NM x NN) -------------
__global__ __launch_bounds__(256) void split_phi_kernel(const float* __restrict__ phi,
                                                        unsigned short* __restrict__ h,
                                                        unsigned short* __restrict__ l) {
    int i = blockIdx.x * 256 + threadIdx.x;
    float v = phi[i];
    unsigned short hh = f2bf(v);
    h[i] = hh;
    l[i] = f2bf(v - bf2f(hh));
}

// -------- precompute: W (NM x NN) -> Wt (NN x NM) transposed + split -------
__global__ __launch_bounds__(256) void transpose_split_W(const float* __restrict__ W,
                                                         unsigned short* __restrict__ th,
                                                         unsigned short* __restrict__ tl) {
    __shared__ float tile[32][33];
    int n0 = blockIdx.x * 32;
    int m0 = blockIdx.y * 32;
    int tx = threadIdx.x;   // 0..31
    int ty = threadIdx.y;   // 0..7
    #pragma unroll
    for (int i = 0; i < 32; i += 8)
        tile[ty + i][tx] = W[(size_t)(m0 + ty + i) * NN + n0 + tx];
    __syncthreads();
    #pragma unroll
    for (int i = 0; i < 32; i += 8) {
        float v = tile[tx][ty + i];
        unsigned short hh = f2bf(v);
        size_t idx = (size_t)(n0 + ty + i) * NM + m0 + tx;
        th[idx] = hh;
        tl[idx] = f2bf(v - bf2f(hh));
    }
}

// ---- GEMM1 (MFMA): Rt(B x NM) = X(B x NN) @ phiT - y, split output ----
#define BM1 128
#define BN1 64
#define BK  32
__global__ __launch_bounds__(256) void gemm1_mfma(const unsigned short* __restrict__ Xh,
                                                  const unsigned short* __restrict__ Xl,
                                                  const unsigned short* __restrict__ Ph,
                                                  const unsigned short* __restrict__ Pl,
                                                  const float* __restrict__ y,
                                                  unsigned short* __restrict__ Rth,
                                                  unsigned short* __restrict__ Rtl) {
    __shared__ unsigned short sAh[BM1 * BK];  // 8KB, row stride 32 elem = 64B
    __shared__ unsigned short sAl[BM1 * BK];
    __shared__ unsigned short sBh[BN1 * BK];  // 4KB
    __shared__ unsigned short sBl[BN1 * BK];

    const int tid = threadIdx.x, wave = tid >> 6, lane = tid & 63;
    const int b0 = blockIdx.x * BM1, n0 = blockIdx.y * BN1;
    const int wm = (wave & 1) * 64, wn = (wave >> 1) * 32;
    const int row16 = lane & 15, quad = lane >> 4;

    f32x4 acc[4][2];
    #pragma unroll
    for (int i = 0; i < 4; i++)
        #pragma unroll
        for (int j = 0; j < 2; j++) acc[i][j] = (f32x4){0.f, 0.f, 0.f, 0.f};

    for (int k0 = 0; k0 < NN; k0 += BK) {
        #pragma unroll
        for (int c = 0; c < 2; ++c) {          // A tiles: 8 chunks of 1KB
            int o = (wave * 2 + c) * 1024 + lane * 16;   // byte offset in tile
            int row = o >> 6, colb = o & 63;
            size_t g = (size_t)(b0 + row) * NN + k0 + (colb >> 1);
            gload16(&Xh[g], (char*)sAh + o);
            gload16(&Xl[g], (char*)sAl + o);
        }
        {                                       // B tiles: 4 chunks of 1KB
            int o = wave * 1024 + lane * 16;
            int nrow = o >> 6, colb = o & 63;
            size_t g = (size_t)(n0 + nrow) * NN + k0 + (colb >> 1);
            gload16(&Ph[g], (char*)sBh + o);
            gload16(&Pl[g], (char*)sBl + o);
        }
        __syncthreads();
        short8 a[4], bh[2], bl[2];
        #pragma unroll
        for (int j = 0; j < 2; ++j) {
            int off = (wn + j * 16 + row16) * 64 + quad * 16;
            bh[j] = *(const short8*)((const char*)sBh + off);
            bl[j] = *(const short8*)((const char*)sBl + off);
        }
        #pragma unroll
        for (int i = 0; i < 4; ++i)
            a[i] = *(const short8*)((const char*)sAh + (wm + i * 16 + row16) * 64 + quad * 16);
        #pragma unroll
        for (int i = 0; i < 4; ++i)
            #pragma unroll
            for (int j = 0; j < 2; ++j) {
                acc[i][j] = __builtin_amdgcn_mfma_f32_16x16x32_bf16(a[i], bh[j], acc[i][j], 0, 0, 0);
                acc[i][j] = __builtin_amdgcn_mfma_f32_16x16x32_bf16(a[i], bl[j], acc[i][j], 0, 0, 0);
            }
        #pragma unroll
        for (int i = 0; i < 4; ++i)
            a[i] = *(const short8*)((const char*)sAl + (wm + i * 16 + row16) * 64 + quad * 16);
        #pragma unroll
        for (int i = 0; i < 4; ++i)
            #pragma unroll
            for (int j = 0; j < 2; ++j)
                acc[i][j] = __builtin_amdgcn_mfma_f32_16x16x32_bf16(a[i], bh[j], acc[i][j], 0, 0, 0);
        __syncthreads();
    }
    #pragma unroll
    for (int i = 0; i < 4; ++i)
        #pragma unroll
        for (int j = 0; j < 2; ++j)
            #pragma unroll
            for (int r = 0; r < 4; ++r) {
                int gm = b0 + wm + i * 16 + quad * 4 + r;
                int gn = n0 + wn + j * 16 + row16;
                size_t idx = (size_t)gm * NM + gn;
                float v = acc[i][j][r] - y[idx];
                unsigned short h = f2bf(v);
                Rth[idx] = h;
                Rtl[idx] = f2bf(v - bf2f(h));
            }
}

// ==== FUSED: V = X - gamma*(Rt @ Wt^T-layout) ; exact top-50 ; X update ====
// Block: 1024 threads (16 waves), tile = 32 batch rows x all 1024 cols.
// A (Rt splits) in padded LDS; B (Wt splits) streamed from global (L2-hot);
// V in registers; per-row exact radix select via LDS histograms aliased
// over the dead A-staging area.
#define FBM 32
#define ASTRIDE 264   // 256 + 8: row bank-rotation 4 -> 2-way (free)
__global__ __launch_bounds__(1024) void fused_gemm2_update(
        const unsigned short* __restrict__ Rth,
        const unsigned short* __restrict__ Rtl,
        const unsigned short* __restrict__ Wth,
        const unsigned short* __restrict__ Wtl,
        unsigned short* __restrict__ Xh,
        unsigned short* __restrict__ Xl,
        const float* __restrict__ gamma,
        const float* __restrict__ theta,
        int it,
        float* __restrict__ out) {
    __shared__ unsigned short sA[2][FBM * ASTRIDE];   // 33792 B
    __shared__ unsigned s_pref[FBM];
    __shared__ unsigned s_rr[FBM];
    __shared__ unsigned s_T[FBM];
    unsigned* hist = reinterpret_cast<unsigned*>(&sA[0][0]);  // 32*257*4 = 32896 B

    const int tid = threadIdx.x, wave = tid >> 6, lane = tid & 63;
    const int row16 = lane & 15, quad = lane >> 4;
    const int b0 = blockIdx.x * FBM;
    const int wn = wave * 64;             // wave owns cols wn..wn+63

    // ---- stage A: Rt tile 32x256, both splits, into padded LDS ----
    {
        int arow = tid >> 5;              // 0..31
        int ac = (tid & 31) * 8;          // col start
        size_t g = (size_t)(b0 + arow) * NM + ac;
        uint4 vh = *reinterpret_cast<const uint4*>(&Rth[g]);
        uint4 vl = *reinterpret_cast<const uint4*>(&Rtl[g]);
        *reinterpret_cast<uint4*>(&sA[0][arow * ASTRIDE + ac]) = vh;
        *reinterpret_cast<uint4*>(&sA[1][arow * ASTRIDE + ac]) = vl;
    }
    __syncthreads();

    // ---- K-loop: acc = Rt @ Wt(rows=n, cols=k) ----
    f32x4 acc[2][4];
    #pragma unroll
    for (int i = 0; i < 2; i++)
        #pragma unroll
        for (int j = 0; j < 4; j++) acc[i][j] = (f32x4){0.f, 0.f, 0.f, 0.f};

    #pragma unroll
    for (int kc = 0; kc < 8; ++kc) {
        short8 bh[4], bl[4];
        #pragma unroll
        for (int j = 0; j < 4; ++j) {
            size_t g = (size_t)(wn + j * 16 + row16) * NM + kc * 32 + quad * 8;
            bh[j] = *(const short8*)&Wth[g];
            bl[j] = *(const short8*)&Wtl[g];
        }
        short8 ah[2], al[2];
        #pragma unroll
        for (int i = 0; i < 2; ++i) {
            int off = (i * 16 + row16) * ASTRIDE + kc * 32 + quad * 8;
            ah[i] = *(const short8*)&sA[0][off];
            al[i] = *(const short8*)&sA[1][off];
        }
        #pragma unroll
        for (int i = 0; i < 2; ++i)
            #pragma unroll
            for (int j = 0; j < 4; ++j) {
                acc[i][j] = __builtin_amdgcn_mfma_f32_16x16x32_bf16(ah[i], bh[j], acc[i][j], 0, 0, 0);
                acc[i][j] = __builtin_amdgcn_mfma_f32_16x16x32_bf16(ah[i], bl[j], acc[i][j], 0, 0, 0);
                acc[i][j] = __builtin_amdgcn_mfma_f32_16x16x32_bf16(al[i], bh[j], acc[i][j], 0, 0, 0);
            }
    }
    __syncthreads();   // done reading sA; hist may now alias it

    // ---- V = X - gamma*acc  (in place into acc) ----
    float gm = gamma[it];
    #pragma unroll
    for (int i = 0; i < 2; ++i)
        #pragma unroll
        for (int j = 0; j < 4; ++j)
            #pragma unroll
            for (int r = 0; r < 4; ++r) {
                int grow = b0 + i * 16 + quad * 4 + r;
                int gcol = wn + j * 16 + row16;
                size_t idx = (size_t)grow * NN + gcol;
                float xo = bf2f(Xh[idx]) + bf2f(Xl[idx]);
                acc[i][j][r] = xo - gm * acc[i][j][r];
            }

    // ---- exact per-row 50th-largest |v|: 4-pass radix (8/8/8/7 bits) ----
    #pragma unroll
    for (int pass = 0; pass < 4; ++pass) {
        for (int p = tid; p < FBM * 257; p += 1024) hist[p] = 0u;
        __syncthreads();
        #pragma unroll
        for (int i = 0; i < 2; ++i)
            #pragma unroll
            for (int j = 0; j < 4; ++j)
                #pragma unroll
                for (int r = 0; r < 4; ++r) {
                    int lrow = i * 16 + quad * 4 + r;
                    unsigned u = __float_as_uint(acc[i][j][r]) & 0x7FFFFFFFu;
                    bool match;
                    unsigned bin;
                    if (pass == 0)      { match = true;                          bin = u >> 23; }
                    else if (pass == 1) { match = (u >> 23) == s_pref[lrow];     bin = (u >> 15) & 255u; }
                    else if (pass == 2) { match = (u >> 15) == s_pref[lrow];     bin = (u >> 7) & 255u; }
                    else                { match = (u >> 7)  == s_pref[lrow];     bin = u & 127u; }
                    if (match) atomicAdd(&hist[lrow * 257 + bin], 1u);
                }
        __syncthreads();
        {   // per-row suffix scan: thread = (row = tid>>5, seg = tid&31)
            int srow = tid >> 5;
            int seg = tid & 31;
            unsigned loc[8];
            unsigned lsum = 0;
            #pragma unroll
            for (int z = 0; z < 8; ++z) {
                loc[z] = hist[srow * 257 + seg * 8 + z];
                lsum += loc[z];
            }
            unsigned s = lsum;
            int l32 = lane & 31;
            #pragma unroll
            for (int o = 1; o < 32; o <<= 1) {
                unsigned t = __shfl_down(s, o, 64);
                if (l32 + o < 32) s += t;
            }
            unsigned rr = (pass == 0) ? (unsigned)TOPK : s_rr[srow];
            unsigned run = s - lsum;   // suffix of all higher segments
            #pragma unroll
            for (int z = 7; z >= 0; --z) {
                unsigned sufThis = run + loc[z];
                if (sufThis >= rr && run < rr) {
                    unsigned bin = (unsigned)(seg * 8 + z);
                    if (pass == 0)      s_pref[srow] = bin;
                    else if (pass < 3)  s_pref[srow] = (s_pref[srow] << 8) | bin;
                    else                s_T[srow] = (s_pref[srow] << 7) | bin;
                    s_rr[srow] = rr - run;
                }
                run = sufThis;
            }
        }
        __syncthreads();
    }

    // ---- epilogue: soft-threshold + exact top-k passthrough ----
    float thv = theta[it];
    #pragma unroll
    for (int i = 0; i < 2; ++i)
        #pragma unroll
        for (int j = 0; j < 4; ++j)
            #pragma unroll
            for (int r = 0; r < 4; ++r) {
                int lrow = i * 16 + quad * 4 + r;
                int grow = b0 + lrow;
                int gcol = wn + j * 16 + row16;
                size_t idx = (size_t)grow * NN + gcol;
                float v = acc[i][j][r];
                unsigned u = __float_as_uint(v) & 0x7FFFFFFFu;
                float xo = bf2f(Xh[idx]) + bf2f(Xl[idx]);   // L1/L2-hot reload
                float th = thv / (10.0f * fabsf(xo) + 1.0f);
                float a = fabsf(v);
                float st = copysignf(fmaxf(a - th, 0.0f), v);
                float outv = (u > s_T[lrow]) ? v : st;
                unsigned short h = f2bf(outv);
                Xh[idx] = h;
                Xl[idx] = f2bf(outv - bf2f(h));
                if (it == NITER - 1) out[idx] = outv;
            }
}

__global__ void tail_kernel(float* __restrict__ out) {
    if (threadIdx.x < 32) out[(size_t)NB * NN + threadIdx.x] = 0.0f;
}

extern "C" void kernel_launch(void* const* d_in, const int* in_sizes, int n_in,
                              void* d_out, int out_size, void* d_ws, size_t ws_size,
                              hipStream_t stream) {
    const float* y     = (const float*)d_in[0];
    const float* phi   = (const float*)d_in[1];
    const float* W     = (const float*)d_in[2];
    const float* gamma = (const float*)d_in[3];
    const float* theta = (const float*)d_in[4];
    float* out = (float*)d_out;

    char* ws = (char*)d_ws;
    size_t off = 0;
    unsigned short* Xh  = (unsigned short*)(ws + off); off += (size_t)NB * NN * 2;  // 32MB
    unsigned short* Xl  = (unsigned short*)(ws + off); off += (size_t)NB * NN * 2;  // 32MB
    unsigned short* Rth = (unsigned short*)(ws + off); off += (size_t)NB * NM * 2;  // 8MB
    unsigned short* Rtl = (unsigned short*)(ws + off); off += (size_t)NB * NM * 2;  // 8MB
    unsigned short* Ph  = (unsigned short*)(ws + off); off += (size_t)NM * NN * 2;  // 512KB
    unsigned short* Pl  = (unsigned short*)(ws + off); off += (size_t)NM * NN * 2;
    unsigned short* Wth = (unsigned short*)(ws + off); off += (size_t)NN * NM * 2;
    unsigned short* Wtl = (unsigned short*)(ws + off); off += (size_t)NN * NM * 2;

    hipMemsetAsync(Xh, 0, (size_t)NB * NN * 2, stream);
    hipMemsetAsync(Xl, 0, (size_t)NB * NN * 2, stream);
    split_phi_kernel<<<(NM * NN) / 256, 256, 0, stream>>>(phi, Ph, Pl);
    transpose_split_W<<<dim3(NN / 32, NM / 32), dim3(32, 8), 0, stream>>>(W, Wth, Wtl);

    for (int it = 0; it < NITER; ++it) {
        gemm1_mfma<<<dim3(NB / BM1, NM / BN1), 256, 0, stream>>>(Xh, Xl, Ph, Pl, y, Rth, Rtl);
        fused_gemm2_update<<<NB / FBM, 1024, 0, stream>>>(Rth, Rtl, Wth, Wtl, Xh, Xl,
                                                          gamma, theta, it, out);
    }
    tail_kernel<<<1, 32, 0, stream>>>(out);
}

// Round 5
// 2878.344 us; speedup vs baseline: 1.0412x; 1.0412x over previous
//
#include <hip/hip_runtime.h>
#include <hip/hip_bf16.h>
#include <cstdint>

#define NB 16384   // batch
#define NM 256     // M
#define NN 1024    // N
#define NITER 16
#define TOPK 50

typedef __attribute__((ext_vector_type(8))) short short8;   // 8 bf16 = 4 VGPRs
typedef __attribute__((ext_vector_type(4))) float f32x4;

__device__ inline unsigned short f2bf(float x) {            // RNE fp32 -> bf16
    unsigned u = __float_as_uint(x);
    return (unsigned short)((u + 0x7FFFu + ((u >> 16) & 1u)) >> 16);
}
__device__ inline float bf2f(unsigned short h) {
    return __uint_as_float(((unsigned)h) << 16);
}
__device__ inline void gload16(const void* g, void* lds) {  // 16B global -> LDS
    __builtin_amdgcn_global_load_lds(
        (const __attribute__((address_space(1))) unsigned*)g,
        (__attribute__((address_space(3))) unsigned*)lds, 16, 0, 0);
}

// ------------- precompute: element-wise split of phi (NM x NN) -------------
__global__ __launch_bounds__(256) void split_phi_kernel(const float* __restrict__ phi,
                                                        unsigned short* __restrict__ h,
                                                        unsigned short* __restrict__ l) {
    int i = blockIdx.x * 256 + threadIdx.x;
    float v = phi[i];
    unsigned short hh = f2bf(v);
    h[i] = hh;
    l[i] = f2bf(v - bf2f(hh));
}

// -------- precompute: W (NM x NN) -> Wt (NN x NM) transposed + split -------
__global__ __launch_bounds__(256) void transpose_split_W(const float* __restrict__ W,
                                                         unsigned short* __restrict__ th,
                                                         unsigned short* __restrict__ tl) {
    __shared__ float tile[32][33];
    int n0 = blockIdx.x * 32;
    int m0 = blockIdx.y * 32;
    int tx = threadIdx.x;   // 0..31
    int ty = threadIdx.y;   // 0..7
    #pragma unroll
    for (int i = 0; i < 32; i += 8)
        tile[ty + i][tx] = W[(size_t)(m0 + ty + i) * NN + n0 + tx];
    __syncthreads();
    #pragma unroll
    for (int i = 0; i < 32; i += 8) {
        float v = tile[tx][ty + i];
        unsigned short hh = f2bf(v);
        size_t idx = (size_t)(n0 + ty + i) * NM + m0 + tx;
        th[idx] = hh;
        tl[idx] = f2bf(v - bf2f(hh));
    }
}

// ---- GEMM1 (MFMA): Rt(B x NM) = X(B x NN) @ phiT - y, split output ----
#define BM1 128
#define BN1 64
#define BK  32
__global__ __launch_bounds__(256) void gemm1_mfma(const unsigned short* __restrict__ Xh,
                                                  const unsigned short* __restrict__ Xl,
                                                  const unsigned short* __restrict__ Ph,
                                                  const unsigned short* __restrict__ Pl,
                                                  const float* __restrict__ y,
                                                  unsigned short* __restrict__ Rth,
                                                  unsigned short* __restrict__ Rtl) {
    __shared__ unsigned short sAh[BM1 * BK];  // 8KB, row stride 32 elem = 64B
    __shared__ unsigned short sAl[BM1 * BK];
    __shared__ unsigned short sBh[BN1 * BK];  // 4KB
    __shared__ unsigned short sBl[BN1 * BK];

    const int tid = threadIdx.x, wave = tid >> 6, lane = tid & 63;
    const int b0 = blockIdx.x * BM1, n0 = blockIdx.y * BN1;
    const int wm = (wave & 1) * 64, wn = (wave >> 1) * 32;
    const int row16 = lane & 15, quad = lane >> 4;

    f32x4 acc[4][2];
    #pragma unroll
    for (int i = 0; i < 4; i++)
        #pragma unroll
        for (int j = 0; j < 2; j++) acc[i][j] = (f32x4){0.f, 0.f, 0.f, 0.f};

    for (int k0 = 0; k0 < NN; k0 += BK) {
        #pragma unroll
        for (int c = 0; c < 2; ++c) {          // A tiles: 8 chunks of 1KB
            int o = (wave * 2 + c) * 1024 + lane * 16;   // byte offset in tile
            int row = o >> 6, colb = o & 63;
            size_t g = (size_t)(b0 + row) * NN + k0 + (colb >> 1);
            gload16(&Xh[g], (char*)sAh + o);
            gload16(&Xl[g], (char*)sAl + o);
        }
        {                                       // B tiles: 4 chunks of 1KB
            int o = wave * 1024 + lane * 16;
            int nrow = o >> 6, colb = o & 63;
            size_t g = (size_t)(n0 + nrow) * NN + k0 + (colb >> 1);
            gload16(&Ph[g], (char*)sBh + o);
            gload16(&Pl[g], (char*)sBl + o);
        }
        __syncthreads();
        short8 a[4], bh[2], bl[2];
        #pragma unroll
        for (int j = 0; j < 2; ++j) {
            int off = (wn + j * 16 + row16) * 64 + quad * 16;
            bh[j] = *(const short8*)((const char*)sBh + off);
            bl[j] = *(const short8*)((const char*)sBl + off);
        }
        #pragma unroll
        for (int i = 0; i < 4; ++i)
            a[i] = *(const short8*)((const char*)sAh + (wm + i * 16 + row16) * 64 + quad * 16);
        #pragma unroll
        for (int i = 0; i < 4; ++i)
            #pragma unroll
            for (int j = 0; j < 2; ++j) {
                acc[i][j] = __builtin_amdgcn_mfma_f32_16x16x32_bf16(a[i], bh[j], acc[i][j], 0, 0, 0);
                acc[i][j] = __builtin_amdgcn_mfma_f32_16x16x32_bf16(a[i], bl[j], acc[i][j], 0, 0, 0);
            }
        #pragma unroll
        for (int i = 0; i < 4; ++i)
            a[i] = *(const short8*)((const char*)sAl + (wm + i * 16 + row16) * 64 + quad * 16);
        #pragma unroll
        for (int i = 0; i < 4; ++i)
            #pragma unroll
            for (int j = 0; j < 2; ++j)
                acc[i][j] = __builtin_amdgcn_mfma_f32_16x16x32_bf16(a[i], bh[j], acc[i][j], 0, 0, 0);
        __syncthreads();
    }
    #pragma unroll
    for (int i = 0; i < 4; ++i)
        #pragma unroll
        for (int j = 0; j < 2; ++j)
            #pragma unroll
            for (int r = 0; r < 4; ++r) {
                int gm = b0 + wm + i * 16 + quad * 4 + r;
                int gn = n0 + wn + j * 16 + row16;
                size_t idx = (size_t)gm * NM + gn;
                float v = acc[i][j][r] - y[idx];
                unsigned short h = f2bf(v);
                Rth[idx] = h;
                Rtl[idx] = f2bf(v - bf2f(h));
            }
}

// ==== FUSED: V = X - gamma*(Rt @ W) ; exact top-50 ; X update ====
// Block: 1024 threads (16 waves), tile = 32 batch rows x all 1024 cols.
// Phase 1: MFMA (A=Rt from padded LDS, B=Wt streamed from L2), V in regs.
// Select: exact per-row 4-pass radix over |v| (hist aliases dead A LDS).
// Phase 2: V round-trips through LDS in 8-row chunks so X writes are
//          fully coalesced 16B stores (fixes the r4 4x write amplification).
#define FBM 32
#define ASTRIDE 264   // 256 + 8
#define VSTRIDE 1032  // 1024 + 8 floats
__global__ __launch_bounds__(1024) void fused_gemm2_update(
        const unsigned short* __restrict__ Rth,
        const unsigned short* __restrict__ Rtl,
        const unsigned short* __restrict__ Wth,
        const unsigned short* __restrict__ Wtl,
        unsigned short* __restrict__ Xh,
        unsigned short* __restrict__ Xl,
        const float* __restrict__ gamma,
        const float* __restrict__ theta,
        int it,
        float* __restrict__ out) {
    // one aliased arena: sA (33792B) -> hist (32896B) -> vbuf (33024B)
    __shared__ __align__(16) char smem_raw[2 * FBM * ASTRIDE * 2];
    unsigned short* sA0 = (unsigned short*)smem_raw;                 // Rt hi
    unsigned short* sA1 = (unsigned short*)smem_raw + FBM * ASTRIDE; // Rt lo
    unsigned* hist = (unsigned*)smem_raw;
    float* vbuf = (float*)smem_raw;
    __shared__ unsigned s_pref[FBM];
    __shared__ unsigned s_rr[FBM];
    __shared__ unsigned s_T[FBM];

    const int tid = threadIdx.x, wave = tid >> 6, lane = tid & 63;
    const int row16 = lane & 15, quad = lane >> 4;
    const int b0 = blockIdx.x * FBM;
    const int wn = wave * 64;             // wave owns cols wn..wn+63
    const float gm = gamma[it];
    const float thv = theta[it];

    // ---- stage A: Rt tile 32x256, both splits, into padded LDS ----
    {
        int arow = tid >> 5;              // 0..31
        int ac = (tid & 31) * 8;          // col start
        size_t g = (size_t)(b0 + arow) * NM + ac;
        uint4 vh = *reinterpret_cast<const uint4*>(&Rth[g]);
        uint4 vl = *reinterpret_cast<const uint4*>(&Rtl[g]);
        *reinterpret_cast<uint4*>(&sA0[arow * ASTRIDE + ac]) = vh;
        *reinterpret_cast<uint4*>(&sA1[arow * ASTRIDE + ac]) = vl;
    }
    __syncthreads();

    // ---- K-loop: acc = Rt @ Wt(rows=n, cols=k) ----
    f32x4 acc[2][4];
    #pragma unroll
    for (int i = 0; i < 2; i++)
        #pragma unroll
        for (int j = 0; j < 4; j++) acc[i][j] = (f32x4){0.f, 0.f, 0.f, 0.f};

    #pragma unroll
    for (int kc = 0; kc < 8; ++kc) {
        short8 bh[4], bl[4];
        #pragma unroll
        for (int j = 0; j < 4; ++j) {
            size_t g = (size_t)(wn + j * 16 + row16) * NM + kc * 32 + quad * 8;
            bh[j] = *(const short8*)&Wth[g];
            bl[j] = *(const short8*)&Wtl[g];
        }
        short8 ah[2], al[2];
        #pragma unroll
        for (int i = 0; i < 2; ++i) {
            int off = (i * 16 + row16) * ASTRIDE + kc * 32 + quad * 8;
            ah[i] = *(const short8*)&sA0[off];
            al[i] = *(const short8*)&sA1[off];
        }
        #pragma unroll
        for (int i = 0; i < 2; ++i)
            #pragma unroll
            for (int j = 0; j < 4; ++j) {
                acc[i][j] = __builtin_amdgcn_mfma_f32_16x16x32_bf16(ah[i], bh[j], acc[i][j], 0, 0, 0);
                acc[i][j] = __builtin_amdgcn_mfma_f32_16x16x32_bf16(ah[i], bl[j], acc[i][j], 0, 0, 0);
                acc[i][j] = __builtin_amdgcn_mfma_f32_16x16x32_bf16(al[i], bh[j], acc[i][j], 0, 0, 0);
            }
    }
    __syncthreads();   // done reading sA; hist may now alias it

    // ---- V = X - gamma*acc  (in place into acc; scattered X read, L2-hot) --
    #pragma unroll
    for (int i = 0; i < 2; ++i)
        #pragma unroll
        for (int j = 0; j < 4; ++j)
            #pragma unroll
            for (int r = 0; r < 4; ++r) {
                int grow = b0 + i * 16 + quad * 4 + r;
                int gcol = wn + j * 16 + row16;
                size_t idx = (size_t)grow * NN + gcol;
                float xo = bf2f(Xh[idx]) + bf2f(Xl[idx]);
                acc[i][j][r] = xo - gm * acc[i][j][r];
            }

    // ---- exact per-row 50th-largest |v|: 4-pass radix (8/8/8/7 bits) ----
    #pragma unroll
    for (int pass = 0; pass < 4; ++pass) {
        for (int p = tid; p < FBM * 257; p += 1024) hist[p] = 0u;
        __syncthreads();
        #pragma unroll
        for (int i = 0; i < 2; ++i)
            #pragma unroll
            for (int j = 0; j < 4; ++j)
                #pragma unroll
                for (int r = 0; r < 4; ++r) {
                    int lrow = i * 16 + quad * 4 + r;
                    unsigned u = __float_as_uint(acc[i][j][r]) & 0x7FFFFFFFu;
                    bool match;
                    unsigned bin;
                    if (pass == 0)      { match = true;                          bin = u >> 23; }
                    else if (pass == 1) { match = (u >> 23) == s_pref[lrow];     bin = (u >> 15) & 255u; }
                    else if (pass == 2) { match = (u >> 15) == s_pref[lrow];     bin = (u >> 7) & 255u; }
                    else                { match = (u >> 7)  == s_pref[lrow];     bin = u & 127u; }
                    if (match) atomicAdd(&hist[lrow * 257 + bin], 1u);
                }
        __syncthreads();
        {   // per-row suffix scan: thread = (row = tid>>5, seg = tid&31)
            int srow = tid >> 5;
            int seg = tid & 31;
            unsigned loc[8];
            unsigned lsum = 0;
            #pragma unroll
            for (int z = 0; z < 8; ++z) {
                loc[z] = hist[srow * 257 + seg * 8 + z];
                lsum += loc[z];
            }
            unsigned s = lsum;
            int l32 = lane & 31;
            #pragma unroll
            for (int o = 1; o < 32; o <<= 1) {
                unsigned t = __shfl_down(s, o, 64);
                if (l32 + o < 32) s += t;
            }
            unsigned rr = (pass == 0) ? (unsigned)TOPK : s_rr[srow];
            unsigned run = s - lsum;   // suffix of all higher segments
            #pragma unroll
            for (int z = 7; z >= 0; --z) {
                unsigned sufThis = run + loc[z];
                if (sufThis >= rr && run < rr) {
                    unsigned bin = (unsigned)(seg * 8 + z);
                    if (pass == 0)      s_pref[srow] = bin;
                    else if (pass < 3)  s_pref[srow] = (s_pref[srow] << 8) | bin;
                    else                s_T[srow] = (s_pref[srow] << 7) | bin;
                    s_rr[srow] = rr - run;
                }
                run = sufThis;
            }
        }
        __syncthreads();
    }

    // ---- phase 2: LDS-transposed epilogue, coalesced X writes ----
    // 4 chunks of 8 rows x 1024 cols (32KB fp32 in vbuf, aliases dead hist).
    #pragma unroll
    for (int c = 0; c < 4; ++c) {
        const int ci = c >> 1;             // acc i index for rows c*8..c*8+7
        const int qlo = (c & 1) << 1;      // participating quads: qlo, qlo+1
        if ((quad >> 1) == (c & 1)) {
            #pragma unroll
            for (int j = 0; j < 4; ++j)
                #pragma unroll
                for (int r = 0; r < 4; ++r) {
                    int vrow = (quad - qlo) * 4 + r;          // 0..7
                    vbuf[vrow * VSTRIDE + wn + j * 16 + row16] = acc[ci][j][r];
                }
        }
        __syncthreads();
        {
            int prow = tid >> 7;                  // 0..7
            int pcol = (tid & 127) * 8;           // 8 elems/thread
            int lrow = c * 8 + prow;
            size_t gidx = (size_t)(b0 + lrow) * NN + pcol;
            float4 v0 = *reinterpret_cast<const float4*>(&vbuf[prow * VSTRIDE + pcol]);
            float4 v1 = *reinterpret_cast<const float4*>(&vbuf[prow * VSTRIDE + pcol + 4]);
            float vv[8] = {v0.x, v0.y, v0.z, v0.w, v1.x, v1.y, v1.z, v1.w};
            uint4 xh8 = *reinterpret_cast<const uint4*>(&Xh[gidx]);
            uint4 xl8 = *reinterpret_cast<const uint4*>(&Xl[gidx]);
            const unsigned short* xhp = reinterpret_cast<const unsigned short*>(&xh8);
            const unsigned short* xlp = reinterpret_cast<const unsigned short*>(&xl8);
            uint4 nh8, nl8;
            unsigned short* nhp = reinterpret_cast<unsigned short*>(&nh8);
            unsigned short* nlp = reinterpret_cast<unsigned short*>(&nl8);
            float ov[8];
            unsigned T = s_T[lrow];
            #pragma unroll
            for (int z = 0; z < 8; ++z) {
                float v = vv[z];
                unsigned u = __float_as_uint(v) & 0x7FFFFFFFu;
                float xo = bf2f(xhp[z]) + bf2f(xlp[z]);
                float th = thv / (10.0f * fabsf(xo) + 1.0f);
                float a = fabsf(v);
                float st = copysignf(fmaxf(a - th, 0.0f), v);
                float outv = (u > T) ? v : st;
                unsigned short h = f2bf(outv);
                nhp[z] = h;
                nlp[z] = f2bf(outv - bf2f(h));
                ov[z] = outv;
            }
            *reinterpret_cast<uint4*>(&Xh[gidx]) = nh8;
            *reinterpret_cast<uint4*>(&Xl[gidx]) = nl8;
            if (it == NITER - 1) {
                *reinterpret_cast<float4*>(&out[gidx]) = *reinterpret_cast<float4*>(&ov[0]);
                *reinterpret_cast<float4*>(&out[gidx + 4]) = *reinterpret_cast<float4*>(&ov[4]);
            }
        }
        __syncthreads();
    }
}

__global__ void tail_kernel(float* __restrict__ out) {
    if (threadIdx.x < 32) out[(size_t)NB * NN + threadIdx.x] = 0.0f;
}

extern "C" void kernel_launch(void* const* d_in, const int* in_sizes, int n_in,
                              void* d_out, int out_size, void* d_ws, size_t ws_size,
                              hipStream_t stream) {
    const float* y     = (const float*)d_in[0];
    const float* phi   = (const float*)d_in[1];
    const float* W     = (const float*)d_in[2];
    const float* gamma = (const float*)d_in[3];
    const float* theta = (const float*)d_in[4];
    float* out = (float*)d_out;

    char* ws = (char*)d_ws;
    size_t off = 0;
    unsigned short* Xh  = (unsigned short*)(ws + off); off += (size_t)NB * NN * 2;  // 32MB
    unsigned short* Xl  = (unsigned short*)(ws + off); off += (size_t)NB * NN * 2;  // 32MB
    unsigned short* Rth = (unsigned short*)(ws + off); off += (size_t)NB * NM * 2;  // 8MB
    unsigned short* Rtl = (unsigned short*)(ws + off); off += (size_t)NB * NM * 2;  // 8MB
    unsigned short* Ph  = (unsigned short*)(ws + off); off += (size_t)NM * NN * 2;  // 512KB
    unsigned short* Pl  = (unsigned short*)(ws + off); off += (size_t)NM * NN * 2;
    unsigned short* Wth = (unsigned short*)(ws + off); off += (size_t)NN * NM * 2;
    unsigned short* Wtl = (unsigned short*)(ws + off); off += (size_t)NN * NM * 2;

    hipMemsetAsync(Xh, 0, (size_t)NB * NN * 2, stream);
    hipMemsetAsync(Xl, 0, (size_t)NB * NN * 2, stream);
    split_phi_kernel<<<(NM * NN) / 256, 256, 0, stream>>>(phi, Ph, Pl);
    transpose_split_W<<<dim3(NN / 32, NM / 32), dim3(32, 8), 0, stream>>>(W, Wth, Wtl);

    for (int it = 0; it < NITER; ++it) {
        gemm1_mfma<<<dim3(NB / BM1, NM / BN1), 256, 0, stream>>>(Xh, Xl, Ph, Pl, y, Rth, Rtl);
        fused_gemm2_update<<<NB / FBM, 1024, 0, stream>>>(Rth, Rtl, Wth, Wtl, Xh, Xl,
                                                          gamma, theta, it, out);
    }
    tail_kernel<<<1, 32, 0, stream>>>(out);
}